// Round 1
// baseline (113.743 us; speedup 1.0000x reference)
//
#include <hip/hip_runtime.h>
#include <math.h>

#define TAU_F 0.3f
#define EPS_F 1e-8f

// Closed-form GWD loss per box:
// sigma = [[A, 0],[0, cz]] with A = R2 diag(dx^2/4, dy^2/4) R2^T, cz = dz^2/4.
// _sqrtm_psd clips eigenvalues at EPS before sqrt -> clip ap1,ap2,czp and the
// eigenvalues of M2 = Sp^1/2 At Sp^1/2 at EPS.
__global__ void gwd_kernel(const float* __restrict__ pred,
                           const float* __restrict__ gt,
                           float* __restrict__ sums, int n) {
    float acc_loss = 0.f, acc_mask = 0.f;
    const int stride = gridDim.x * blockDim.x;
    for (int i = blockIdx.x * blockDim.x + threadIdx.x; i < n; i += stride) {
        const float* p = pred + (size_t)i * 7;
        const float* g = gt   + (size_t)i * 7;
        float px = p[0], py = p[1], pz = p[2];
        float pdx = p[3], pdy = p[4], pdz = p[5], pth = p[6];
        float tx = g[0], ty = g[1], tz = g[2];
        float tdx = g[3], tdy = g[4], tdz = g[5], tth = g[6];

        float dx = px - tx, dy = py - ty, dz = pz - tz;
        float mu_dist = dx * dx + dy * dy + dz * dz;

        float ap1 = 0.25f * pdx * pdx, ap2 = 0.25f * pdy * pdy, czp = 0.25f * pdz * pdz;
        float at1 = 0.25f * tdx * tdx, at2 = 0.25f * tdy * tdy, czt = 0.25f * tdz * tdz;

        float sp, cp; sincosf(pth, &sp, &cp);
        float st, ct; sincosf(tth, &st, &ct);
        float cp2 = cp * cp, sp2 = sp * sp, cpsp = cp * sp;
        float ct2 = ct * ct, st2 = st * st, ctst = ct * st;

        // sigma_t 2x2 block (unclipped)
        float At11 = at1 * ct2 + at2 * st2;
        float At22 = at1 * st2 + at2 * ct2;
        float At12 = (at1 - at2) * ctst;

        // clipped sigma_p 2x2 block (= (Sp^1/2)^2 after eigen clipping)
        float ap1c = fmaxf(ap1, EPS_F), ap2c = fmaxf(ap2, EPS_F);
        float Ap11 = ap1c * cp2 + ap2c * sp2;
        float Ap22 = ap1c * sp2 + ap2c * cp2;
        float Ap12 = (ap1c - ap2c) * cpsp;

        // M2 = Sp^1/2 At Sp^1/2: tr = tr(At * Ap'), det = det(At)*det(Ap')
        float T = At11 * Ap11 + 2.f * At12 * Ap12 + At22 * Ap22;
        float D = (at1 * at2) * (ap1c * ap2c);
        float r = sqrtf(fmaxf(T * T - 4.f * D, 0.f));
        float lm1 = 0.5f * (T + r), lm2 = 0.5f * (T - r);
        float tr_sqrt_M2 = sqrtf(fmaxf(lm1, EPS_F)) + sqrtf(fmaxf(lm2, EPS_F));

        // z-axis is decoupled
        float czpc = fmaxf(czp, EPS_F);
        float z_sqrt = sqrtf(fmaxf(czpc * czt, EPS_F));

        float cov = (ap1 + ap2 + czp) + (at1 + at2 + czt)
                    - 2.f * (tr_sqrt_M2 + z_sqrt);
        float w2 = mu_dist + cov;

        float det_t = fmaxf(at1 * at2 * czt, EPS_F);
        float det_term = cbrtf(det_t);
        float loss = 1.f - expf(-w2 / (TAU_F * det_term));
        float mask = (tx != 0.f) ? 1.f : 0.f;
        acc_loss += loss * mask;
        acc_mask += mask;
    }

    // wave-64 shuffle reduction
    for (int off = 32; off; off >>= 1) {
        acc_loss += __shfl_down(acc_loss, off, 64);
        acc_mask += __shfl_down(acc_mask, off, 64);
    }
    __shared__ float sl[8], sm[8];
    int lane = threadIdx.x & 63, wave = threadIdx.x >> 6;
    if (lane == 0) { sl[wave] = acc_loss; sm[wave] = acc_mask; }
    __syncthreads();
    if (threadIdx.x == 0) {
        float tl = 0.f, tm = 0.f;
        int nw = blockDim.x >> 6;
        for (int w = 0; w < nw; ++w) { tl += sl[w]; tm += sm[w]; }
        atomicAdd(&sums[0], tl);
        atomicAdd(&sums[1], tm);
    }
}

__global__ void gwd_finalize(const float* __restrict__ sums,
                             float* __restrict__ out) {
    if (threadIdx.x == 0 && blockIdx.x == 0) {
        out[0] = sums[0] / (sums[1] + EPS_F);
    }
}

extern "C" void kernel_launch(void* const* d_in, const int* in_sizes, int n_in,
                              void* d_out, int out_size, void* d_ws, size_t ws_size,
                              hipStream_t stream) {
    const float* pred = (const float*)d_in[0];
    const float* gt   = (const float*)d_in[1];
    float* out  = (float*)d_out;
    float* sums = (float*)d_ws;
    int n = in_sizes[0] / 7;  // B*N boxes

    hipMemsetAsync(sums, 0, 2 * sizeof(float), stream);

    const int block = 256;
    const int grid  = 1024;  // ~4 boxes/thread grid-stride; 4 blocks/CU
    gwd_kernel<<<grid, block, 0, stream>>>(pred, gt, sums, n);
    gwd_finalize<<<1, 64, 0, stream>>>(sums, out);
}

// Round 3
// 109.097 us; speedup vs baseline: 1.0426x; 1.0426x over previous
//
#include <hip/hip_runtime.h>
#include <math.h>

#define TAU_F 0.3f
#define EPS_F 1e-8f

#define GRID 1024
#define BLOCK 256

typedef float f32x4 __attribute__((ext_vector_type(4)));

// Closed-form GWD loss per box:
// sigma = [[A, 0],[0, cz]] with A = R2 diag(dx^2/4, dy^2/4) R2^T, cz = dz^2/4.
// _sqrtm_psd clips eigenvalues at EPS before sqrt -> clip ap1,ap2 (and final
// eigenvalues of M2 = Sp^1/2 At Sp^1/2) at EPS; z-axis is fully decoupled.
__global__ __launch_bounds__(BLOCK) void gwd_kernel(
        const f32x4* __restrict__ pred4,
        const f32x4* __restrict__ gt4,
        float* __restrict__ partials) {
    const int tid = blockIdx.x * BLOCK + threadIdx.x;

    // Each thread handles 4 boxes = 28 floats = 7 float4 per input array.
    float pa[28], ga[28];
    {
        const f32x4* pp = pred4 + (size_t)tid * 7;
        const f32x4* gg = gt4   + (size_t)tid * 7;
#pragma unroll
        for (int j = 0; j < 7; ++j) {
            f32x4 v = __builtin_nontemporal_load(pp + j);
            pa[4*j+0] = v.x; pa[4*j+1] = v.y; pa[4*j+2] = v.z; pa[4*j+3] = v.w;
            f32x4 w = __builtin_nontemporal_load(gg + j);
            ga[4*j+0] = w.x; ga[4*j+1] = w.y; ga[4*j+2] = w.z; ga[4*j+3] = w.w;
        }
    }

    float acc_loss = 0.f, acc_mask = 0.f;
#pragma unroll
    for (int k = 0; k < 4; ++k) {
        const float* p = pa + 7 * k;
        const float* g = ga + 7 * k;
        float dx = p[0] - g[0], dy = p[1] - g[1], dz = p[2] - g[2];
        float mu_dist = dx * dx + dy * dy + dz * dz;

        float ap1 = 0.25f * p[3] * p[3], ap2 = 0.25f * p[4] * p[4], czp = 0.25f * p[5] * p[5];
        float at1 = 0.25f * g[3] * g[3], at2 = 0.25f * g[4] * g[4], czt = 0.25f * g[5] * g[5];

        float sp, cp; sincosf(p[6], &sp, &cp);
        float st, ct; sincosf(g[6], &st, &ct);
        float cp2 = cp * cp, sp2 = sp * sp, cpsp = cp * sp;
        float ct2 = ct * ct, st2 = st * st, ctst = ct * st;

        // sigma_t 2x2 block (unclipped)
        float At11 = at1 * ct2 + at2 * st2;
        float At22 = at1 * st2 + at2 * ct2;
        float At12 = (at1 - at2) * ctst;

        // clipped sigma_p 2x2 block (= (Sp^1/2)^2 after eigen clipping)
        float ap1c = fmaxf(ap1, EPS_F), ap2c = fmaxf(ap2, EPS_F);
        float Ap11 = ap1c * cp2 + ap2c * sp2;
        float Ap22 = ap1c * sp2 + ap2c * cp2;
        float Ap12 = (ap1c - ap2c) * cpsp;

        // M2 = Sp^1/2 At Sp^1/2: tr = tr(At*Ap'), det = det(At)*det(Ap')
        float T = At11 * Ap11 + 2.f * At12 * Ap12 + At22 * Ap22;
        float D = (at1 * at2) * (ap1c * ap2c);
        float r = sqrtf(fmaxf(T * T - 4.f * D, 0.f));
        float tr_sqrt_M2 = sqrtf(fmaxf(0.5f * (T + r), EPS_F)) +
                           sqrtf(fmaxf(0.5f * (T - r), EPS_F));

        // z-axis decoupled
        float z_sqrt = sqrtf(fmaxf(fmaxf(czp, EPS_F) * czt, EPS_F));

        float cov = (ap1 + ap2 + czp) + (at1 + at2 + czt)
                    - 2.f * (tr_sqrt_M2 + z_sqrt);
        float w2 = mu_dist + cov;

        float det_term = cbrtf(fmaxf(at1 * at2 * czt, EPS_F));
        float loss = 1.f - expf(-w2 / (TAU_F * det_term));
        float mask = (g[0] != 0.f) ? 1.f : 0.f;
        acc_loss += loss * mask;
        acc_mask += mask;
    }

    // wave-64 shuffle reduction
#pragma unroll
    for (int off = 32; off; off >>= 1) {
        acc_loss += __shfl_down(acc_loss, off, 64);
        acc_mask += __shfl_down(acc_mask, off, 64);
    }
    __shared__ float sl[4], sm[4];
    int lane = threadIdx.x & 63, wave = threadIdx.x >> 6;
    if (lane == 0) { sl[wave] = acc_loss; sm[wave] = acc_mask; }
    __syncthreads();
    if (threadIdx.x == 0) {
        float tl = sl[0] + sl[1] + sl[2] + sl[3];
        float tm = sm[0] + sm[1] + sm[2] + sm[3];
        partials[blockIdx.x]        = tl;
        partials[GRID + blockIdx.x] = tm;
    }
}

// Reduce GRID partial pairs -> scalar loss.
__global__ __launch_bounds__(1024) void gwd_finalize(
        const float* __restrict__ partials, float* __restrict__ out) {
    int tid = threadIdx.x;
    float l = partials[tid];
    float m = partials[GRID + tid];
#pragma unroll
    for (int off = 32; off; off >>= 1) {
        l += __shfl_down(l, off, 64);
        m += __shfl_down(m, off, 64);
    }
    __shared__ float sl[16], sm[16];
    int lane = tid & 63, wave = tid >> 6;
    if (lane == 0) { sl[wave] = l; sm[wave] = m; }
    __syncthreads();
    if (tid == 0) {
        float tl = 0.f, tm = 0.f;
#pragma unroll
        for (int w = 0; w < 16; ++w) { tl += sl[w]; tm += sm[w]; }
        out[0] = tl / (tm + EPS_F);
    }
}

extern "C" void kernel_launch(void* const* d_in, const int* in_sizes, int n_in,
                              void* d_out, int out_size, void* d_ws, size_t ws_size,
                              hipStream_t stream) {
    const f32x4* pred = (const f32x4*)d_in[0];
    const f32x4* gt   = (const f32x4*)d_in[1];
    float* out      = (float*)d_out;
    float* partials = (float*)d_ws;

    // B*N = 1048576 boxes = 262144 quad-boxes = GRID*BLOCK threads exactly.
    gwd_kernel<<<GRID, BLOCK, 0, stream>>>(pred, gt, partials);
    gwd_finalize<<<1, 1024, 0, stream>>>(partials, out);
}

// Round 5
// 101.247 us; speedup vs baseline: 1.1234x; 1.0775x over previous
//
#include <hip/hip_runtime.h>
#include <math.h>

#define TAU_F 0.3f
#define EPS_F 1e-8f

#define GRID 2048
#define BLOCK 256

typedef float f32x2 __attribute__((ext_vector_type(2)));

// Closed-form GWD loss per box:
// sigma = [[A, 0],[0, cz]] with A = R2 diag(dx^2/4, dy^2/4) R2^T, cz = dz^2/4.
// _sqrtm_psd clips eigenvalues at EPS before sqrt -> clip ap1,ap2 (and final
// eigenvalues of M2 = Sp^1/2 At Sp^1/2) at EPS; z-axis is fully decoupled.
// 2 boxes/thread (14 floats = 7 x float2, 8B-aligned) to keep VGPR <= 64
// for full 8-waves/SIMD occupancy on this streaming-bound kernel.
__global__ __launch_bounds__(BLOCK) void gwd_kernel(
        const f32x2* __restrict__ pred2,
        const f32x2* __restrict__ gt2,
        float* __restrict__ partials) {
    const int tid = blockIdx.x * BLOCK + threadIdx.x;

    float pa[14], ga[14];
    {
        const f32x2* pp = pred2 + (size_t)tid * 7;
        const f32x2* gg = gt2   + (size_t)tid * 7;
#pragma unroll
        for (int j = 0; j < 7; ++j) {
            f32x2 v = __builtin_nontemporal_load(pp + j);
            pa[2*j+0] = v.x; pa[2*j+1] = v.y;
            f32x2 w = __builtin_nontemporal_load(gg + j);
            ga[2*j+0] = w.x; ga[2*j+1] = w.y;
        }
    }

    float acc_loss = 0.f, acc_mask = 0.f;
#pragma unroll
    for (int k = 0; k < 2; ++k) {
        const float* p = pa + 7 * k;
        const float* g = ga + 7 * k;
        float dx = p[0] - g[0], dy = p[1] - g[1], dz = p[2] - g[2];
        float mu_dist = dx * dx + dy * dy + dz * dz;

        float ap1 = 0.25f * p[3] * p[3], ap2 = 0.25f * p[4] * p[4], czp = 0.25f * p[5] * p[5];
        float at1 = 0.25f * g[3] * g[3], at2 = 0.25f * g[4] * g[4], czt = 0.25f * g[5] * g[5];

        float sp, cp; __sincosf(p[6], &sp, &cp);
        float st, ct; __sincosf(g[6], &st, &ct);
        float cp2 = cp * cp, sp2 = sp * sp, cpsp = cp * sp;
        float ct2 = ct * ct, st2 = st * st, ctst = ct * st;

        // sigma_t 2x2 block (unclipped)
        float At11 = at1 * ct2 + at2 * st2;
        float At22 = at1 * st2 + at2 * ct2;
        float At12 = (at1 - at2) * ctst;

        // clipped sigma_p 2x2 block (= (Sp^1/2)^2 after eigen clipping)
        float ap1c = fmaxf(ap1, EPS_F), ap2c = fmaxf(ap2, EPS_F);
        float Ap11 = ap1c * cp2 + ap2c * sp2;
        float Ap22 = ap1c * sp2 + ap2c * cp2;
        float Ap12 = (ap1c - ap2c) * cpsp;

        // M2 = Sp^1/2 At Sp^1/2: tr = tr(At*Ap'), det = det(At)*det(Ap')
        float T = At11 * Ap11 + 2.f * At12 * Ap12 + At22 * Ap22;
        float D = (at1 * at2) * (ap1c * ap2c);
        float r = sqrtf(fmaxf(T * T - 4.f * D, 0.f));
        float tr_sqrt_M2 = sqrtf(fmaxf(0.5f * (T + r), EPS_F)) +
                           sqrtf(fmaxf(0.5f * (T - r), EPS_F));

        // z-axis decoupled
        float z_sqrt = sqrtf(fmaxf(fmaxf(czp, EPS_F) * czt, EPS_F));

        float cov = (ap1 + ap2 + czp) + (at1 + at2 + czt)
                    - 2.f * (tr_sqrt_M2 + z_sqrt);
        float w2 = mu_dist + cov;

        // det_term = cbrt(det_t); det_t >= EPS > 0 so log2 is safe.
        // v_log_f32 is log2, v_exp_f32 is exp2.
        float det_t = fmaxf(at1 * at2 * czt, EPS_F);
        float det_term = __builtin_amdgcn_exp2f(
            0.33333333f * __builtin_amdgcn_logf(det_t));
        float loss = 1.f - __expf(-w2 / (TAU_F * det_term));
        float mask = (g[0] != 0.f) ? 1.f : 0.f;
        acc_loss += loss * mask;
        acc_mask += mask;
    }

    // wave-64 shuffle reduction
#pragma unroll
    for (int off = 32; off; off >>= 1) {
        acc_loss += __shfl_down(acc_loss, off, 64);
        acc_mask += __shfl_down(acc_mask, off, 64);
    }
    __shared__ float sl[4], sm[4];
    int lane = threadIdx.x & 63, wave = threadIdx.x >> 6;
    if (lane == 0) { sl[wave] = acc_loss; sm[wave] = acc_mask; }
    __syncthreads();
    if (threadIdx.x == 0) {
        float tl = sl[0] + sl[1] + sl[2] + sl[3];
        float tm = sm[0] + sm[1] + sm[2] + sm[3];
        partials[blockIdx.x]            = tl;
        partials[2 * GRID + blockIdx.x] = tm;
    }
}

// Reduce GRID partial pairs -> scalar loss. GRID=2048, 1024 threads x 2.
__global__ __launch_bounds__(1024) void gwd_finalize(
        const float* __restrict__ partials, float* __restrict__ out) {
    int tid = threadIdx.x;
    float l = partials[tid] + partials[tid + 1024];
    float m = partials[2 * GRID + tid] + partials[2 * GRID + tid + 1024];
#pragma unroll
    for (int off = 32; off; off >>= 1) {
        l += __shfl_down(l, off, 64);
        m += __shfl_down(m, off, 64);
    }
    __shared__ float sl[16], sm[16];
    int lane = tid & 63, wave = tid >> 6;
    if (lane == 0) { sl[wave] = l; sm[wave] = m; }
    __syncthreads();
    if (tid == 0) {
        float tl = 0.f, tm = 0.f;
#pragma unroll
        for (int w = 0; w < 16; ++w) { tl += sl[w]; tm += sm[w]; }
        out[0] = tl / (tm + EPS_F);
    }
}

extern "C" void kernel_launch(void* const* d_in, const int* in_sizes, int n_in,
                              void* d_out, int out_size, void* d_ws, size_t ws_size,
                              hipStream_t stream) {
    const f32x2* pred = (const f32x2*)d_in[0];
    const f32x2* gt   = (const f32x2*)d_in[1];
    float* out      = (float*)d_out;
    float* partials = (float*)d_ws;

    // B*N = 1048576 boxes = 524288 thread-pairs = GRID*BLOCK threads exactly.
    gwd_kernel<<<GRID, BLOCK, 0, stream>>>(pred, gt, partials);
    gwd_finalize<<<1, 1024, 0, stream>>>(partials, out);
}